// Round 1
// baseline (946.609 us; speedup 1.0000x reference)
//
#include <hip/hip_runtime.h>
#include <stdint.h>
#include <stddef.h>

typedef __attribute__((ext_vector_type(8))) short short8;
typedef __attribute__((ext_vector_type(4))) float f32x4;

#define NB 2048
#define HD 512
#define SD 256

#define A_STR 40      // shorts per A-tile row (32 k + 8 pad)
#define W_STR 40      // shorts per W-tile row (32 k + 8 pad)
#define A_BUF 5120    // shorts per A buffer (128*40)
#define W_BUF 20480   // shorts per W buffer (512*40)
#define LDS_BYTES (2*A_BUF*2 + 2*W_BUF*2 + 128*4)  // 102912

__device__ __forceinline__ short f2bf(float x) {
  union { float f; uint32_t u; } v; v.f = x;
  uint32_t r = v.u + 0x7fffu + ((v.u >> 16) & 1u);
  return (short)(r >> 16);
}

__device__ __forceinline__ float fast_tanh(float x) {
  x = fminf(fmaxf(x, -15.f), 15.f);
  float e = __expf(2.f * x);
  return __fdividef(e - 1.f, e + 1.f);
}

// ---- Wt[j][k] = bf16(W[k][j]) : one-time transpose+convert ----
__global__ __launch_bounds__(256) void wconv_kernel(const float* __restrict__ W,
                                                    short* __restrict__ Wt) {
  __shared__ float tile[32][33];
  const int bx = blockIdx.x;
  const int tk0 = (bx & 15) * 32;
  const int tj0 = (bx >> 4) * 32;
  const int lx = threadIdx.x & 31;
  const int ly = threadIdx.x >> 5;
  for (int r = 0; r < 4; ++r) {
    int yy = ly + r * 8;
    tile[yy][lx] = W[(size_t)(tk0 + yy) * HD + tj0 + lx];
  }
  __syncthreads();
  for (int r = 0; r < 4; ++r) {
    int yy = ly + r * 8;
    Wt[(size_t)(tj0 + yy) * HD + tk0 + lx] = f2bf(tile[lx][yy]);
  }
}

// ---- alignment[n][s] = sum_j tanh( sum_k hs[n,k,s]*W[k,j] + b[j] ) * c[j] ----
// block: one (n, 128-row s-half). 512 threads = 8 waves (2m x 4j grid).
// A-tile [128 s][32 k] + W-tile [512 j][32 k] double-buffered; full-j acc in regs.
__global__ void __launch_bounds__(512, 2)
align_kernel(const float* __restrict__ hs, const short* __restrict__ Wt,
             const float* __restrict__ bias, const float* __restrict__ ctx,
             float* __restrict__ align_out)
{
  extern __shared__ char smem[];
  short* As = (short*)smem;                       // 2 x [128][40]
  short* Ws = (short*)(smem + 2 * A_BUF * 2);     // 2 x [512][40]
  float* abuf = (float*)(smem + 2 * A_BUF * 2 + 2 * W_BUF * 2);  // [128]

  const int tid = threadIdx.x;
  const int n = blockIdx.x >> 1;
  const int s0 = (blockIdx.x & 1) * 128;
  const float* hsn = hs + (size_t)n * (HD * SD);

  if (tid < 128) abuf[tid] = 0.f;

  // prologue: stage k-block 0 into buffer 0
  {
    #pragma unroll
    for (int half = 0; half < 2; ++half) {
      int v = tid + half * 512;
      int mq = v & 31, kk = v >> 5;
      float4 va = *(const float4*)(hsn + (size_t)kk * SD + s0 + mq * 4);
      short* w = As + (mq * 4) * A_STR + kk;
      w[0] = f2bf(va.x); w[A_STR] = f2bf(va.y);
      w[2 * A_STR] = f2bf(va.z); w[3 * A_STR] = f2bf(va.w);
    }
    #pragma unroll
    for (int ii = 0; ii < 4; ++ii) {
      int u = tid + ii * 512;
      int kg = u & 3, j = u >> 2;
      *(short8*)(Ws + j * W_STR + kg * 8) =
          *(const short8*)(Wt + (size_t)j * HD + kg * 8);
    }
  }
  __syncthreads();

  const int lane = tid & 63;
  const int wid = tid >> 6;
  const int wm = wid >> 2;   // 0..1 : m (s-row) half
  const int wj = wid & 3;    // 0..3 : j quarter (128 wide)
  const int l15 = lane & 15;
  const int lg = lane >> 4;

  f32x4 acc[4][8];
  #pragma unroll
  for (int i = 0; i < 4; ++i)
    #pragma unroll
    for (int p = 0; p < 8; ++p)
      acc[i][p] = (f32x4){0.f, 0.f, 0.f, 0.f};

  for (int kt = 0; kt < 16; ++kt) {
    const int cur = kt & 1;
    const short* Ac = As + cur * A_BUF;
    const short* Wc = Ws + cur * W_BUF;

    short8 af[4], wf[8];
    {
      const short* Ab = Ac + (wm * 64 + l15) * A_STR + lg * 8;
      #pragma unroll
      for (int i = 0; i < 4; ++i) af[i] = *(const short8*)(Ab + i * 16 * A_STR);
      const short* Wb = Wc + (wj * 128 + l15) * W_STR + lg * 8;
      #pragma unroll
      for (int p = 0; p < 8; ++p) wf[p] = *(const short8*)(Wb + p * 16 * W_STR);
    }

    if (kt < 15) {  // stage k-block kt+1 into the other buffer (overlaps MFMAs)
      const int kb = (kt + 1) * 32;
      short* Ad = As + (cur ^ 1) * A_BUF;
      short* Wd = Ws + (cur ^ 1) * W_BUF;
      #pragma unroll
      for (int half = 0; half < 2; ++half) {
        int v = tid + half * 512;
        int mq = v & 31, kk = v >> 5;
        float4 va = *(const float4*)(hsn + (size_t)(kb + kk) * SD + s0 + mq * 4);
        short* w = Ad + (mq * 4) * A_STR + kk;
        w[0] = f2bf(va.x); w[A_STR] = f2bf(va.y);
        w[2 * A_STR] = f2bf(va.z); w[3 * A_STR] = f2bf(va.w);
      }
      #pragma unroll
      for (int ii = 0; ii < 4; ++ii) {
        int u = tid + ii * 512;
        int kg = u & 3, j = u >> 2;
        *(short8*)(Wd + j * W_STR + kg * 8) =
            *(const short8*)(Wt + (size_t)j * HD + kb + kg * 8);
      }
    }

    #pragma unroll
    for (int i = 0; i < 4; ++i)
      #pragma unroll
      for (int p = 0; p < 8; ++p)
        acc[i][p] = __builtin_amdgcn_mfma_f32_16x16x32_bf16(af[i], wf[p], acc[i][p], 0, 0, 0);

    __syncthreads();
  }

  // epilogue: tanh + dot with c, reduce j
  float part[16];
  #pragma unroll
  for (int q = 0; q < 16; ++q) part[q] = 0.f;
  #pragma unroll
  for (int p = 0; p < 8; ++p) {
    const int j = wj * 128 + p * 16 + l15;
    const float bj = bias[j];
    const float cj = ctx[j];
    #pragma unroll
    for (int i = 0; i < 4; ++i)
      #pragma unroll
      for (int r = 0; r < 4; ++r)
        part[i * 4 + r] += fast_tanh(acc[i][p][r] + bj) * cj;
  }
  #pragma unroll
  for (int q = 0; q < 16; ++q) {
    part[q] += __shfl_xor(part[q], 1);
    part[q] += __shfl_xor(part[q], 2);
    part[q] += __shfl_xor(part[q], 4);
    part[q] += __shfl_xor(part[q], 8);
  }
  if (l15 == 0) {
    #pragma unroll
    for (int i = 0; i < 4; ++i)
      #pragma unroll
      for (int r = 0; r < 4; ++r)
        atomicAdd(&abuf[wm * 64 + i * 16 + lg * 4 + r], part[i * 4 + r]);
  }
  __syncthreads();
  if (tid < 128) align_out[(size_t)n * SD + s0 + tid] = abuf[tid];
}

// ---- softmax over s + context[n,h] = sum_s attn[s]*hs[n,h,s] ----
__global__ __launch_bounds__(256) void ctx_kernel(const float* __restrict__ hs,
                                                  const float* __restrict__ align_in,
                                                  float* __restrict__ out)
{
  __shared__ __align__(16) float attn_s[256];
  __shared__ float red[8];
  const int n = blockIdx.x;
  const int t = threadIdx.x;
  const int lane = t & 63, wid = t >> 6;

  float a = align_in[(size_t)n * 256 + t];
  float m = a;
  #pragma unroll
  for (int off = 32; off; off >>= 1) m = fmaxf(m, __shfl_xor(m, off));
  if (lane == 0) red[wid] = m;
  __syncthreads();
  m = fmaxf(fmaxf(red[0], red[1]), fmaxf(red[2], red[3]));
  float e = __expf(a - m);
  float s = e;
  #pragma unroll
  for (int off = 32; off; off >>= 1) s += __shfl_xor(s, off);
  if (lane == 0) red[4 + wid] = s;
  __syncthreads();
  s = red[4] + red[5] + red[6] + red[7];
  attn_s[t] = e / s;
  __syncthreads();

  const int grp = t & 7;      // s-chunk of 32
  const int hrow = t >> 3;    // 0..31
  float av[32];
  #pragma unroll
  for (int u = 0; u < 8; ++u) {
    float4 v = *(const float4*)&attn_s[grp * 32 + u * 4];
    av[4*u+0] = v.x; av[4*u+1] = v.y; av[4*u+2] = v.z; av[4*u+3] = v.w;
  }
  const float* hb = hs + (size_t)n * (HD * SD) + grp * 32;
  for (int it = 0; it < 16; ++it) {
    const int h = it * 32 + hrow;
    const float4* p = (const float4*)(hb + (size_t)h * SD);
    float acc = 0.f;
    #pragma unroll
    for (int u = 0; u < 8; ++u) {
      float4 v = p[u];
      acc += av[4*u+0]*v.x + av[4*u+1]*v.y + av[4*u+2]*v.z + av[4*u+3]*v.w;
    }
    acc += __shfl_xor(acc, 1);
    acc += __shfl_xor(acc, 2);
    acc += __shfl_xor(acc, 4);
    if (grp == 0) out[(size_t)n * HD + h] = acc;
  }
}

extern "C" void kernel_launch(void* const* d_in, const int* in_sizes, int n_in,
                              void* d_out, int out_size, void* d_ws, size_t ws_size,
                              hipStream_t stream) {
  (void)in_sizes; (void)n_in; (void)out_size; (void)ws_size;
  const float* hs = (const float*)d_in[0];
  const float* W  = (const float*)d_in[1];
  const float* b  = (const float*)d_in[2];
  const float* c  = (const float*)d_in[3];
  float* out = (float*)d_out;

  float* align_ws = (float*)d_ws;                                  // 2 MB
  short* Wt = (short*)((char*)d_ws + (size_t)NB * SD * 4);         // 512 KB

  wconv_kernel<<<256, 256, 0, stream>>>(W, Wt);
  align_kernel<<<4096, 512, LDS_BYTES, stream>>>(hs, Wt, b, c, align_ws);
  ctx_kernel<<<NB, 256, 0, stream>>>(hs, align_ws, out);
}